// Round 14
// baseline (219.364 us; speedup 1.0000x reference)
//
#include <hip/hip_runtime.h>
#include <hip/hip_bf16.h>

namespace {
constexpr int D       = 128;
constexpr int K       = 1024;
constexpr int M_TOTAL = 65536;   // 16 * 4096
constexpr int BM      = 128;     // rows per block: 4 waves x 32 rows
constexpr int NCT     = K / 16;  // 64 code-tiles of 16 codes
constexpr float TAU   = 5.0e-5f; // covers numpy-fp32 quantization span + scorer err
// d_ws layout
constexpr size_t WS_CN  = 0;                 // float[1024]         (4 KB)
constexpr size_t WS_BH  = 4096;              // short[131072]       (256 KB)
constexpr size_t WS_BL  = 4096 + 262144;     // short[131072]       (256 KB)
constexpr size_t WS_REQ = 4096 + 2 * 262144; // 528,384 B (confirmed available, R11-R13)
}

typedef short bf16x8 __attribute__((ext_vector_type(8)));
typedef float f32x4  __attribute__((ext_vector_type(4)));
typedef float f32x4v __attribute__((ext_vector_type(4)));

static __device__ __forceinline__ unsigned short bfbits(float x) {
  __hip_bfloat16 h = __float2bfloat16(x);   // RNE
  return *reinterpret_cast<unsigned short*>(&h);
}
static __device__ __forceinline__ float bfhi2f(unsigned short h) {
  return __uint_as_float(((unsigned)h) << 16);
}
static __device__ __forceinline__ void split8(float4 a, float4 b,
                                              bf16x8& ph, bf16x8& pl) {
  float v[8] = {a.x, a.y, a.z, a.w, b.x, b.y, b.z, b.w};
#pragma unroll
  for (int e = 0; e < 8; ++e) {
    unsigned short h = bfbits(v[e]);
    unsigned short l = bfbits(v[e] - bfhi2f(h));
    ph[e] = (short)h;
    pl[e] = (short)l;
  }
}
// non-temporal 16B load/store (keep streaming z / outputs OUT of L2 so the
// codebook fragment planes stay L2-resident — the R13 thrash fix)
static __device__ __forceinline__ float4 ntload4(const float* p) {
  f32x4v v = __builtin_nontemporal_load(reinterpret_cast<const f32x4v*>(p));
  return make_float4(v.x, v.y, v.z, v.w);
}
static __device__ __forceinline__ void ntstore4(float* p, float4 s) {
  f32x4v v = {s.x, s.y, s.z, s.w};
  __builtin_nontemporal_store(v, reinterpret_cast<f32x4v*>(p));
}

// ---------------- prep 1: Cn[k] = numpy-pairwise fp32 sum of cb[k,d]^2 ----------------
__global__ void vq_prep(const float* __restrict__ cb, float* __restrict__ Cn) {
  int k = blockIdx.x * 256 + threadIdx.x;
  if (k >= K) return;
  const float* c = cb + (size_t)k * D;
  float r8[8];
#pragma unroll
  for (int j = 0; j < 8; ++j) r8[j] = __fmul_rn(c[j], c[j]);
  for (int i = 8; i < D; i += 8) {
#pragma unroll
    for (int j = 0; j < 8; ++j)
      r8[j] = __fadd_rn(r8[j], __fmul_rn(c[i + j], c[i + j]));
  }
  Cn[k] = __fadd_rn(__fadd_rn(__fadd_rn(r8[0], r8[1]), __fadd_rn(r8[2], r8[3])),
                    __fadd_rn(__fadd_rn(r8[4], r8[5]), __fadd_rn(r8[6], r8[7])));
}

// ---------------- prep 2: codebook -> hi/lo bf16 planes, fragment-linear (validated) ----
// slot u = (ct*4 + ks)*64 + lane ; code = ct*16 + (lane&15), d = ks*32 + (lane>>4)*8 + e
__global__ void vq_frag(const float* __restrict__ cb,
                        short* __restrict__ Bh, short* __restrict__ Bl) {
  int g = blockIdx.x * 256 + threadIdx.x;           // 0 .. 16383
  int code = (g >> 8) * 16 + (g & 15);
  int d0   = ((g >> 6) & 3) * 32 + ((g >> 4) & 3) * 8;
  const float* p = cb + (size_t)code * D + d0;
  float4 a = *reinterpret_cast<const float4*>(p);
  float4 b = *reinterpret_cast<const float4*>(p + 4);
  bf16x8 ph, pl;
  split8(a, b, ph, pl);
  *reinterpret_cast<bf16x8*>(Bh + (size_t)g * 8) = ph;
  *reinterpret_cast<bf16x8*>(Bl + (size_t)g * 8) = pl;
}

// ---------------- FAST main: R13 structure + non-temporal streaming traffic ----------
__global__ __launch_bounds__(256, 2) void vq_main_frag(
    const float* __restrict__ z, const float* __restrict__ cb,
    const float* __restrict__ Cn,
    const short* __restrict__ BhG, const short* __restrict__ BlG,
    float* __restrict__ out_zq, float* __restrict__ out_q,
    float* __restrict__ out_c, float* __restrict__ out_i) {
  // [dbuf][tile-in-group][chunk(plane*4+ks)][512 shorts=1KB] : 32 KB
  __shared__ __align__(16) short Bbuf[2][2][8][512];
  __shared__ float CnS[K];          // 4 KB
  __shared__ float sRed[256];
  __shared__ int   iRed[256];
  __shared__ int   idxArr[BM];
  __shared__ int   hardRows[BM];
  __shared__ int   hardCnt;

  const int t    = threadIdx.x;
  const int wave = t >> 6;
  const int lane = t & 63;
  const int col  = lane & 15;
  const int baseRow = blockIdx.x * BM;

  if (t == 0) hardCnt = 0;
  for (int i = t; i < K; i += 256) CnS[i] = Cn[i];

  // A fragments: wave's 32 z-rows (2 sets of 16) -> persistent VGPRs (NT: z is stream-once)
  bf16x8 ah[2][4], al[2][4];
#pragma unroll
  for (int set = 0; set < 2; ++set) {
    const float* zL = z + (size_t)(baseRow + wave * 32 + set * 16 + col) * D + (lane >> 4) * 8;
#pragma unroll
    for (int ks = 0; ks < 4; ++ks) {
      float4 a = ntload4(zL + ks * 32);
      float4 b = ntload4(zL + ks * 32 + 4);
      split8(a, b, ah[set][ks], al[set][ks]);
    }
  }

  float s1[2][4], s2[2][4]; int i1[2][4];
#pragma unroll
  for (int s = 0; s < 2; ++s)
#pragma unroll
    for (int i = 0; i < 4; ++i) {
      s1[s][i] = 3.402823466e+38f; s2[s][i] = 3.402823466e+38f; i1[s][i] = 0;
    }

  // stage tile ct into Bbuf[b_][ti_]: each wave DMAs 2 of 8 chunks (validated R12/R13)
#define STAGE(b_, ti_, ct_)                                                         \
  { _Pragma("unroll")                                                               \
    for (int i_ = 0; i_ < 2; ++i_) {                                                \
      int c_  = wave * 2 + i_;                                                      \
      int p_  = c_ >> 2, ks_ = c_ & 3;                                              \
      const short* gsrc_ = (p_ ? BlG : BhG) +                                       \
                           (size_t)(((ct_) * 4 + ks_) * 64 + lane) * 8;             \
      __builtin_amdgcn_global_load_lds(                                             \
          (const __attribute__((address_space(1))) void*)gsrc_,                     \
          (__attribute__((address_space(3))) void*)&Bbuf[b_][ti_][c_][0], 16, 0, 0);\
    } }

  // compute tile ct from Bbuf[b_][ti_] against BOTH A-sets (numerics = R13, absmax 0.0078)
#define COMP(b_, ti_, ct_)                                                          \
  { _Pragma("unroll")                                                               \
    for (int ks_ = 0; ks_ < 4; ++ks_) {                                             \
      bh_c[ks_] = *reinterpret_cast<const bf16x8*>(&Bbuf[b_][ti_][ks_][lane * 8]);  \
      bl_c[ks_] = *reinterpret_cast<const bf16x8*>(&Bbuf[b_][ti_][4 + ks_][lane * 8]); \
    }                                                                               \
    const int code_ = (ct_) * 16 + col;                                             \
    const float cn_ = CnS[code_];                                                   \
    _Pragma("unroll")                                                               \
    for (int set_ = 0; set_ < 2; ++set_) {                                          \
      f32x4 aA = (f32x4){0.f,0.f,0.f,0.f};                                          \
      f32x4 aB = (f32x4){0.f,0.f,0.f,0.f};                                          \
      f32x4 aC = (f32x4){0.f,0.f,0.f,0.f};                                          \
      _Pragma("unroll")                                                             \
      for (int ks_ = 0; ks_ < 4; ++ks_) {                                           \
        aA = __builtin_amdgcn_mfma_f32_16x16x32_bf16(ah[set_][ks_], bh_c[ks_], aA, 0,0,0); \
        aB = __builtin_amdgcn_mfma_f32_16x16x32_bf16(ah[set_][ks_], bl_c[ks_], aB, 0,0,0); \
        aC = __builtin_amdgcn_mfma_f32_16x16x32_bf16(al[set_][ks_], bh_c[ks_], aC, 0,0,0); \
      }                                                                             \
      _Pragma("unroll")                                                             \
      for (int reg_ = 0; reg_ < 4; ++reg_) {                                        \
        float S = fmaf(-2.0f, (aA[reg_] + aB[reg_]) + aC[reg_], cn_);               \
        if (S < s1[set_][reg_]) { s2[set_][reg_] = s1[set_][reg_];                  \
                                  s1[set_][reg_] = S; i1[set_][reg_] = code_; }     \
        else if (S < s2[set_][reg_]) { s2[set_][reg_] = S; }                        \
      }                                                                             \
    } }

  bf16x8 bh_c[4], bl_c[4];
  STAGE(0, 0, 0); STAGE(0, 1, 1);
  __syncthreads();                       // drain group 0; CnS + hardCnt visible
  for (int g = 0; g < NCT / 2; ++g) {
    const int b = g & 1;
    if (g + 1 < NCT / 2) { STAGE(b ^ 1, 0, 2 * g + 2); STAGE(b ^ 1, 1, 2 * g + 3); }
    COMP(b, 0, 2 * g);
    COMP(b, 1, 2 * g + 1);
    __syncthreads();                     // drain next group; protect buf reuse
  }
#undef STAGE
#undef COMP

  // cross-lane (16-col group) min1/min2 merge
#pragma unroll
  for (int m = 1; m < 16; m <<= 1) {
#pragma unroll
    for (int set = 0; set < 2; ++set)
#pragma unroll
      for (int reg = 0; reg < 4; ++reg) {
        float os1 = __shfl_xor(s1[set][reg], m, 64);
        float os2 = __shfl_xor(s2[set][reg], m, 64);
        int   oi  = __shfl_xor(i1[set][reg], m, 64);
        if (os1 < s1[set][reg]) {
          s2[set][reg] = fminf(s1[set][reg], os2);
          s1[set][reg] = os1; i1[set][reg] = oi;
        } else {
          s2[set][reg] = fminf(s2[set][reg], os1);
        }
      }
  }

  if (col == 0) {
#pragma unroll
    for (int set = 0; set < 2; ++set)
#pragma unroll
      for (int reg = 0; reg < 4; ++reg) {
        int row = wave * 32 + set * 16 + (lane >> 4) * 4 + reg;
        idxArr[row] = i1[set][reg];
        if (s2[set][reg] - s1[set][reg] < TAU) {
          int p = atomicAdd(&hardCnt, 1);
          hardRows[p] = row;
        }
      }
  }
  __syncthreads();

  // hard rows: bit-exact numpy-fp32 full-K rescan (R4-validated recipe)
  const int nh = hardCnt;
  for (int f = 0; f < nh; ++f) {
    const int row = hardRows[f];
    const float*  zp  = z + (size_t)(baseRow + row) * D;
    const float4* zp4 = reinterpret_cast<const float4*>(zp);
    float r8[8];
#pragma unroll
    for (int j = 0; j < 8; ++j) r8[j] = __fmul_rn(zp[j], zp[j]);
    for (int i = 8; i < D; i += 8) {
#pragma unroll
      for (int j = 0; j < 8; ++j)
        r8[j] = __fadd_rn(r8[j], __fmul_rn(zp[i + j], zp[i + j]));
    }
    float A = __fadd_rn(__fadd_rn(__fadd_rn(r8[0], r8[1]), __fadd_rn(r8[2], r8[3])),
                        __fadd_rn(__fadd_rn(r8[4], r8[5]), __fadd_rn(r8[6], r8[7])));
    const int kb = t * 4;
    float acc4[4] = {0.f, 0.f, 0.f, 0.f};
    const float4* cp0 = reinterpret_cast<const float4*>(cb + (size_t)(kb + 0) * D);
    const float4* cp1 = reinterpret_cast<const float4*>(cb + (size_t)(kb + 1) * D);
    const float4* cp2 = reinterpret_cast<const float4*>(cb + (size_t)(kb + 2) * D);
    const float4* cp3 = reinterpret_cast<const float4*>(cb + (size_t)(kb + 3) * D);
#pragma unroll 8
    for (int d4 = 0; d4 < 32; ++d4) {
      float4 zv = zp4[d4];
      float4 c0 = cp0[d4], c1 = cp1[d4], c2 = cp2[d4], c3 = cp3[d4];
      acc4[0] = fmaf(zv.x, c0.x, acc4[0]); acc4[0] = fmaf(zv.y, c0.y, acc4[0]);
      acc4[0] = fmaf(zv.z, c0.z, acc4[0]); acc4[0] = fmaf(zv.w, c0.w, acc4[0]);
      acc4[1] = fmaf(zv.x, c1.x, acc4[1]); acc4[1] = fmaf(zv.y, c1.y, acc4[1]);
      acc4[1] = fmaf(zv.z, c1.z, acc4[1]); acc4[1] = fmaf(zv.w, c1.w, acc4[1]);
      acc4[2] = fmaf(zv.x, c2.x, acc4[2]); acc4[2] = fmaf(zv.y, c2.y, acc4[2]);
      acc4[2] = fmaf(zv.z, c2.z, acc4[2]); acc4[2] = fmaf(zv.w, c2.w, acc4[2]);
      acc4[3] = fmaf(zv.x, c3.x, acc4[3]); acc4[3] = fmaf(zv.y, c3.y, acc4[3]);
      acc4[3] = fmaf(zv.z, c3.z, acc4[3]); acc4[3] = fmaf(zv.w, c3.w, acc4[3]);
    }
    float bd = 3.402823466e+38f; int bi = 0;
#pragma unroll
    for (int c = 0; c < 4; ++c) {
      float dist = __fadd_rn(__fsub_rn(A, __fmul_rn(2.0f, acc4[c])), CnS[kb + c]);
      if (dist < bd) { bd = dist; bi = kb + c; }
    }
    sRed[t] = bd; iRed[t] = bi;
    __syncthreads();
    for (int w = 128; w > 0; w >>= 1) {
      if (t < w) {
        float o = sRed[t + w]; int oi = iRed[t + w];
        if (o < sRed[t] || (o == sRed[t] && oi < iRed[t])) { sRed[t] = o; iRed[t] = oi; }
      }
      __syncthreads();
    }
    if (t == 0) idxArr[row] = iRed[0];
    __syncthreads();
  }

  // epilogue: gather z_q, STE, losses, index (2 threads per row; NT stream in/out)
  {
    int r = t >> 1, q = t & 1;
    int idx = idxArr[r];
    size_t m = (size_t)baseRow + r;
    const float* cq  = cb + (size_t)idx * D + q * 64;
    const float* zr4 = z + m * D + q * 64;
    float*       o4  = out_zq + m * D + q * 64;
    float sum = 0.f;
#pragma unroll
    for (int e = 0; e < 16; ++e) {
      float4 cv = *reinterpret_cast<const float4*>(cq + e * 4);   // cb: keep cached
      float4 zv = ntload4(zr4 + e * 4);                           // z: stream
      float dx = cv.x - zv.x, dy = cv.y - zv.y, dz = cv.z - zv.z, dw = cv.w - zv.w;
      float4 st;
      st.x = zv.x + dx; st.y = zv.y + dy; st.z = zv.z + dz; st.w = zv.w + dw;
      ntstore4(o4 + e * 4, st);                                   // z_q: stream
      sum = fmaf(dx, dx, sum); sum = fmaf(dy, dy, sum);
      sum = fmaf(dz, dz, sum); sum = fmaf(dw, dw, sum);
    }
    sum += __shfl_xor(sum, 1, 64);
    if (q == 0) {
      float lv = sum * 0.0078125f;   // /128
      __builtin_nontemporal_store(lv, &out_q[m]);
      __builtin_nontemporal_store(lv, &out_c[m]);
      __builtin_nontemporal_store((float)idx, &out_i[m]);
    }
  }
}

// ---------------- FALLBACK main: R4 kernel verbatim (validated, ~320 us) ---------------
__global__ __launch_bounds__(256) void vq_main_fp32(
    const float* __restrict__ z, const float* __restrict__ cb,
    const float* __restrict__ Cn,
    float* __restrict__ out_zq, float* __restrict__ out_q,
    float* __restrict__ out_c, float* __restrict__ out_i) {
  __shared__ float Zt[64 * D];
  __shared__ float Ct[64 * D];
  __shared__ float Arow[64];
  __shared__ int   idxArr[64];

  const int t  = threadIdx.x;
  const int ty = t >> 4;
  const int tx = t & 15;
  const int baseRow = blockIdx.x * 64;

  for (int s = t; s < 64 * (D / 4); s += 256) {
    int r = s >> 5, d4 = s & 31;
    float4 v = reinterpret_cast<const float4*>(z)[(size_t)(baseRow + r) * (D / 4) + d4];
    int colx = d4 ^ (r & 7);
    *reinterpret_cast<float4*>(&Zt[r * D + colx * 4]) = v;
  }
  __syncthreads();

  if (t < 64) {
    const int rs = t & 7;
    float r8[8];
#pragma unroll
    for (int j = 0; j < 8; ++j) {
      float v = Zt[t * D + (((j >> 2) ^ rs) << 2) + (j & 3)];
      r8[j] = __fmul_rn(v, v);
    }
    for (int i = 8; i < D; i += 8) {
#pragma unroll
      for (int j = 0; j < 8; ++j) {
        int d = i + j;
        float v = Zt[t * D + (((d >> 2) ^ rs) << 2) + (d & 3)];
        r8[j] = __fadd_rn(r8[j], __fmul_rn(v, v));
      }
    }
    Arow[t] = __fadd_rn(__fadd_rn(__fadd_rn(r8[0], r8[1]), __fadd_rn(r8[2], r8[3])),
                        __fadd_rn(__fadd_rn(r8[4], r8[5]), __fadd_rn(r8[6], r8[7])));
  }

  float s1[4]; int i1[4];
#pragma unroll
  for (int i = 0; i < 4; ++i) { s1[i] = 3.402823466e+38f; i1[i] = 0; }

  const int zsw = ty & 7;
  const int csw = tx & 7;

  for (int kt = 0; kt < 16; ++kt) {
    __syncthreads();
    for (int s = t; s < 64 * (D / 4); s += 256) {
      int r = s >> 5, d4 = s & 31;
      float4 v = reinterpret_cast<const float4*>(cb)[(size_t)(kt * 64 + r) * (D / 4) + d4];
      int colx = d4 ^ (r & 7);
      *reinterpret_cast<float4*>(&Ct[r * D + colx * 4]) = v;
    }
    __syncthreads();

    float acc[4][4];
#pragma unroll
    for (int i = 0; i < 4; ++i)
#pragma unroll
      for (int j = 0; j < 4; ++j) acc[i][j] = 0.f;

    for (int d4 = 0; d4 < 32; ++d4) {
      float4 za[4], cv[4];
      int zc = (d4 ^ zsw) * 4;
      int cc = (d4 ^ csw) * 4;
#pragma unroll
      for (int i = 0; i < 4; ++i)
        za[i] = *reinterpret_cast<const float4*>(&Zt[(ty + 16 * i) * D + zc]);
#pragma unroll
      for (int j = 0; j < 4; ++j)
        cv[j] = *reinterpret_cast<const float4*>(&Ct[(tx + 16 * j) * D + cc]);
#pragma unroll
      for (int i = 0; i < 4; ++i)
#pragma unroll
        for (int j = 0; j < 4; ++j) {
          acc[i][j] = fmaf(za[i].x, cv[j].x, acc[i][j]);
          acc[i][j] = fmaf(za[i].y, cv[j].y, acc[i][j]);
          acc[i][j] = fmaf(za[i].z, cv[j].z, acc[i][j]);
          acc[i][j] = fmaf(za[i].w, cv[j].w, acc[i][j]);
        }
    }

    float ch[4]; int kg[4];
#pragma unroll
    for (int j = 0; j < 4; ++j) {
      kg[j] = kt * 64 + tx + 16 * j;
      ch[j] = Cn[kg[j]];
    }
#pragma unroll
    for (int i = 0; i < 4; ++i) {
      float a = Arow[ty + 16 * i];
#pragma unroll
      for (int j = 0; j < 4; ++j) {
        float dist = __fadd_rn(__fsub_rn(a, __fmul_rn(2.0f, acc[i][j])), ch[j]);
        if (dist < s1[i]) { s1[i] = dist; i1[i] = kg[j]; }
      }
    }
  }

#pragma unroll
  for (int m = 1; m < 16; m <<= 1) {
#pragma unroll
    for (int i = 0; i < 4; ++i) {
      float os = __shfl_xor(s1[i], m, 64);
      int   oi = __shfl_xor(i1[i], m, 64);
      if (os < s1[i] || (os == s1[i] && oi < i1[i])) { s1[i] = os; i1[i] = oi; }
    }
  }

  if (tx == 0) {
#pragma unroll
    for (int i = 0; i < 4; ++i) idxArr[ty + 16 * i] = i1[i];
  }
  __syncthreads();

  {
    int r = t >> 2, q = t & 3;
    int idx = idxArr[r];
    size_t m = (size_t)baseRow + r;
    const float4* cq = reinterpret_cast<const float4*>(cb + (size_t)idx * D);
    const float4* zr = reinterpret_cast<const float4*>(z + m * D);
    float4*       o4 = reinterpret_cast<float4*>(out_zq + m * D);
    float sum = 0.f;
#pragma unroll
    for (int e = 0; e < 8; ++e) {
      int d4 = q * 8 + e;
      float4 cv = cq[d4];
      float4 zv = zr[d4];
      float dx = cv.x - zv.x, dy = cv.y - zv.y, dz = cv.z - zv.z, dw = cv.w - zv.w;
      float4 st;
      st.x = zv.x + dx; st.y = zv.y + dy; st.z = zv.z + dz; st.w = zv.w + dw;
      o4[d4] = st;
      sum = fmaf(dx, dx, sum); sum = fmaf(dy, dy, sum);
      sum = fmaf(dz, dz, sum); sum = fmaf(dw, dw, sum);
    }
    sum += __shfl_xor(sum, 1, 64);
    sum += __shfl_xor(sum, 2, 64);
    if (q == 0) {
      float lv = sum * 0.0078125f;
      out_q[m] = lv;
      out_c[m] = lv;
      out_i[m] = (float)idx;
    }
  }
}

extern "C" void kernel_launch(void* const* d_in, const int* in_sizes, int n_in,
                              void* d_out, int out_size, void* d_ws, size_t ws_size,
                              hipStream_t stream) {
  const float* z  = (const float*)d_in[0];   // [16,4096,128] fp32
  const float* cb = (const float*)d_in[1];   // [1024,128] fp32

  float* out0 = (float*)d_out;               // z_q_ste  [M,128]
  float* out1 = out0 + (size_t)M_TOTAL * D;  // quant_loss [M]
  float* out2 = out1 + M_TOTAL;              // commit_loss [M]
  float* out3 = out2 + M_TOTAL;              // indices (as float) [M]

  float* Cn = (float*)((char*)d_ws + WS_CN);
  vq_prep<<<(K + 255) / 256, 256, 0, stream>>>(cb, Cn);

  if (ws_size >= WS_REQ) {
    short* Bh = (short*)((char*)d_ws + WS_BH);
    short* Bl = (short*)((char*)d_ws + WS_BL);
    vq_frag<<<64, 256, 0, stream>>>(cb, Bh, Bl);
    vq_main_frag<<<M_TOTAL / BM, 256, 0, stream>>>(z, cb, Cn, Bh, Bl,
                                                   out0, out1, out2, out3);
  } else {
    vq_main_fp32<<<M_TOTAL / 64, 256, 0, stream>>>(z, cb, Cn, out0, out1, out2, out3);
  }
}

// Round 15
// 209.619 us; speedup vs baseline: 1.0465x; 1.0465x over previous
//
#include <hip/hip_runtime.h>
#include <hip/hip_bf16.h>

namespace {
constexpr int D       = 128;
constexpr int K       = 1024;
constexpr int M_TOTAL = 65536;   // 16 * 4096
constexpr int BM      = 128;     // rows per block: 4 waves x 32 rows
constexpr int NCT     = K / 16;  // 64 code-tiles of 16 codes
constexpr float TAU   = 5.0e-5f; // covers numpy-fp32 quantization span + scorer err
// d_ws layout
constexpr size_t WS_CN  = 0;                 // float[1024]         (4 KB)
constexpr size_t WS_BH  = 4096;              // short[131072]       (256 KB)
constexpr size_t WS_BL  = 4096 + 262144;     // short[131072]       (256 KB)
constexpr size_t WS_REQ = 4096 + 2 * 262144; // 528,384 B (confirmed available, R11-R14)
}

typedef short bf16x8 __attribute__((ext_vector_type(8)));
typedef float f32x4  __attribute__((ext_vector_type(4)));

static __device__ __forceinline__ unsigned short bfbits(float x) {
  __hip_bfloat16 h = __float2bfloat16(x);   // RNE
  return *reinterpret_cast<unsigned short*>(&h);
}
static __device__ __forceinline__ float bfhi2f(unsigned short h) {
  return __uint_as_float(((unsigned)h) << 16);
}
static __device__ __forceinline__ void split8(float4 a, float4 b,
                                              bf16x8& ph, bf16x8& pl) {
  float v[8] = {a.x, a.y, a.z, a.w, b.x, b.y, b.z, b.w};
#pragma unroll
  for (int e = 0; e < 8; ++e) {
    unsigned short h = bfbits(v[e]);
    unsigned short l = bfbits(v[e] - bfhi2f(h));
    ph[e] = (short)h;
    pl[e] = (short)l;
  }
}

// ---------------- prep 1: Cn[k] = numpy-pairwise fp32 sum of cb[k,d]^2 ----------------
__global__ void vq_prep(const float* __restrict__ cb, float* __restrict__ Cn) {
  int k = blockIdx.x * 256 + threadIdx.x;
  if (k >= K) return;
  const float* c = cb + (size_t)k * D;
  float r8[8];
#pragma unroll
  for (int j = 0; j < 8; ++j) r8[j] = __fmul_rn(c[j], c[j]);
  for (int i = 8; i < D; i += 8) {
#pragma unroll
    for (int j = 0; j < 8; ++j)
      r8[j] = __fadd_rn(r8[j], __fmul_rn(c[i + j], c[i + j]));
  }
  Cn[k] = __fadd_rn(__fadd_rn(__fadd_rn(r8[0], r8[1]), __fadd_rn(r8[2], r8[3])),
                    __fadd_rn(__fadd_rn(r8[4], r8[5]), __fadd_rn(r8[6], r8[7])));
}

// ---------------- prep 2: codebook -> hi/lo bf16 planes, fragment-linear (validated) ----
// slot u = (ct*4 + ks)*64 + lane ; code = ct*16 + (lane&15), d = ks*32 + (lane>>4)*8 + e
__global__ void vq_frag(const float* __restrict__ cb,
                        short* __restrict__ Bh, short* __restrict__ Bl) {
  int g = blockIdx.x * 256 + threadIdx.x;           // 0 .. 16383
  int code = (g >> 8) * 16 + (g & 15);
  int d0   = ((g >> 6) & 3) * 32 + ((g >> 4) & 3) * 8;
  const float* p = cb + (size_t)code * D + d0;
  float4 a = *reinterpret_cast<const float4*>(p);
  float4 b = *reinterpret_cast<const float4*>(p + 4);
  bf16x8 ph, pl;
  split8(a, b, ph, pl);
  *reinterpret_cast<bf16x8*>(Bh + (size_t)g * 8) = ph;
  *reinterpret_cast<bf16x8*>(Bl + (size_t)g * 8) = pl;
}

// ---------------- FAST main: 4-deep counted-vmcnt pipeline (T3+T4), raw barriers -------
__global__ __launch_bounds__(256, 2) void vq_main_frag(
    const float* __restrict__ z, const float* __restrict__ cb,
    const float* __restrict__ Cn,
    const short* __restrict__ BhG, const short* __restrict__ BlG,
    float* __restrict__ out_zq, float* __restrict__ out_q,
    float* __restrict__ out_c, float* __restrict__ out_i) {
  // 4 single-tile buffers: [buf][chunk(plane*4+ks)][512 shorts = 1 KB] = 32 KB
  __shared__ __align__(16) short Bbuf[4][8][512];
  __shared__ float CnS[K];          // 4 KB
  __shared__ float sRed[256];
  __shared__ int   iRed[256];
  __shared__ int   idxArr[BM];
  __shared__ int   hardRows[BM];
  __shared__ int   hardCnt;

  const int t    = threadIdx.x;
  const int wave = t >> 6;
  const int lane = t & 63;
  const int col  = lane & 15;
  const int baseRow = blockIdx.x * BM;

  if (t == 0) hardCnt = 0;
  for (int i = t; i < K; i += 256) CnS[i] = Cn[i];

  // A fragments: wave's 32 z-rows (2 sets of 16) -> persistent VGPRs (validated mapping)
  bf16x8 ah[2][4], al[2][4];
#pragma unroll
  for (int set = 0; set < 2; ++set) {
    const float* zL = z + (size_t)(baseRow + wave * 32 + set * 16 + col) * D + (lane >> 4) * 8;
#pragma unroll
    for (int ks = 0; ks < 4; ++ks) {
      float4 a = *reinterpret_cast<const float4*>(zL + ks * 32);
      float4 b = *reinterpret_cast<const float4*>(zL + ks * 32 + 4);
      split8(a, b, ah[set][ks], al[set][ks]);
    }
  }

  float s1[2][4], s2[2][4]; int i1[2][4];
#pragma unroll
  for (int s = 0; s < 2; ++s)
#pragma unroll
    for (int i = 0; i < 4; ++i) {
      s1[s][i] = 3.402823466e+38f; s2[s][i] = 3.402823466e+38f; i1[s][i] = 0;
    }

  // stage one tile into buf bi_: each wave DMAs its 2 of the 8 chunks (validated R12-R14)
#define STAGE(ct_, bi_)                                                             \
  { _Pragma("unroll")                                                               \
    for (int i_ = 0; i_ < 2; ++i_) {                                                \
      int c_  = wave * 2 + i_;                                                      \
      int p_  = c_ >> 2, ks_ = c_ & 3;                                              \
      const short* gsrc_ = (p_ ? BlG : BhG) +                                       \
                           (size_t)(((ct_) * 4 + ks_) * 64 + lane) * 8;             \
      __builtin_amdgcn_global_load_lds(                                             \
          (const __attribute__((address_space(1))) void*)gsrc_,                     \
          (__attribute__((address_space(3))) void*)&Bbuf[bi_][c_][0], 16, 0, 0);    \
    } }

  // compute one tile from buf bi_ against BOTH A-sets (numerics = R13, absmax 0.0078)
#define COMP(bi_, ct_)                                                              \
  { bf16x8 bh_c[4], bl_c[4];                                                        \
    _Pragma("unroll")                                                               \
    for (int ks_ = 0; ks_ < 4; ++ks_) {                                             \
      bh_c[ks_] = *reinterpret_cast<const bf16x8*>(&Bbuf[bi_][ks_][lane * 8]);      \
      bl_c[ks_] = *reinterpret_cast<const bf16x8*>(&Bbuf[bi_][4 + ks_][lane * 8]);  \
    }                                                                               \
    const int code_ = (ct_) * 16 + col;                                             \
    const float cn_ = CnS[code_];                                                   \
    __builtin_amdgcn_s_setprio(1);                                                  \
    _Pragma("unroll")                                                               \
    for (int set_ = 0; set_ < 2; ++set_) {                                          \
      f32x4 aA = (f32x4){0.f,0.f,0.f,0.f};                                          \
      f32x4 aB = (f32x4){0.f,0.f,0.f,0.f};                                          \
      f32x4 aC = (f32x4){0.f,0.f,0.f,0.f};                                          \
      _Pragma("unroll")                                                             \
      for (int ks_ = 0; ks_ < 4; ++ks_) {                                           \
        aA = __builtin_amdgcn_mfma_f32_16x16x32_bf16(ah[set_][ks_], bh_c[ks_], aA, 0,0,0); \
        aB = __builtin_amdgcn_mfma_f32_16x16x32_bf16(ah[set_][ks_], bl_c[ks_], aB, 0,0,0); \
        aC = __builtin_amdgcn_mfma_f32_16x16x32_bf16(al[set_][ks_], bh_c[ks_], aC, 0,0,0); \
      }                                                                             \
      _Pragma("unroll")                                                             \
      for (int reg_ = 0; reg_ < 4; ++reg_) {                                        \
        float S = fmaf(-2.0f, (aA[reg_] + aB[reg_]) + aC[reg_], cn_);               \
        if (S < s1[set_][reg_]) { s2[set_][reg_] = s1[set_][reg_];                  \
                                  s1[set_][reg_] = S; i1[set_][reg_] = code_; }     \
        else if (S < s2[set_][reg_]) { s2[set_][reg_] = S; }                        \
      }                                                                             \
    }                                                                               \
    __builtin_amdgcn_s_setprio(0); }

  // phase: counted wait (2 newer tiles stay in flight) -> raw barrier -> compute -> prefetch
#define PHASE(t_, bi_)                                                              \
  { asm volatile("s_waitcnt vmcnt(4)" ::: "memory");                                \
    __builtin_amdgcn_s_barrier();                                                   \
    __builtin_amdgcn_sched_barrier(0);                                              \
    COMP(bi_, t_);                                                                  \
    STAGE(((t_) + 3) & 63, ((bi_) + 3) & 3); }

  __syncthreads();   // CnS + hardCnt visible; A-loads drained (once, before pipeline)
  STAGE(0, 0); STAGE(1, 1); STAGE(2, 2);   // 6 loads/thread in flight
  for (int g = 0; g < NCT; g += 4) {
    PHASE(g + 0, 0);
    PHASE(g + 1, 1);
    PHASE(g + 2, 2);
    PHASE(g + 3, 3);
  }
#undef PHASE
#undef STAGE
#undef COMP

  __syncthreads();   // full drain (wrapped prefetches) before LDS reuse

  // cross-lane (16-col group) min1/min2 merge
#pragma unroll
  for (int m = 1; m < 16; m <<= 1) {
#pragma unroll
    for (int set = 0; set < 2; ++set)
#pragma unroll
      for (int reg = 0; reg < 4; ++reg) {
        float os1 = __shfl_xor(s1[set][reg], m, 64);
        float os2 = __shfl_xor(s2[set][reg], m, 64);
        int   oi  = __shfl_xor(i1[set][reg], m, 64);
        if (os1 < s1[set][reg]) {
          s2[set][reg] = fminf(s1[set][reg], os2);
          s1[set][reg] = os1; i1[set][reg] = oi;
        } else {
          s2[set][reg] = fminf(s2[set][reg], os1);
        }
      }
  }

  if (col == 0) {
#pragma unroll
    for (int set = 0; set < 2; ++set)
#pragma unroll
      for (int reg = 0; reg < 4; ++reg) {
        int row = wave * 32 + set * 16 + (lane >> 4) * 4 + reg;
        idxArr[row] = i1[set][reg];
        if (s2[set][reg] - s1[set][reg] < TAU) {
          int p = atomicAdd(&hardCnt, 1);
          hardRows[p] = row;
        }
      }
  }
  __syncthreads();

  // hard rows: bit-exact numpy-fp32 full-K rescan (R4-validated recipe)
  const int nh = hardCnt;
  for (int f = 0; f < nh; ++f) {
    const int row = hardRows[f];
    const float*  zp  = z + (size_t)(baseRow + row) * D;
    const float4* zp4 = reinterpret_cast<const float4*>(zp);
    float r8[8];
#pragma unroll
    for (int j = 0; j < 8; ++j) r8[j] = __fmul_rn(zp[j], zp[j]);
    for (int i = 8; i < D; i += 8) {
#pragma unroll
      for (int j = 0; j < 8; ++j)
        r8[j] = __fadd_rn(r8[j], __fmul_rn(zp[i + j], zp[i + j]));
    }
    float A = __fadd_rn(__fadd_rn(__fadd_rn(r8[0], r8[1]), __fadd_rn(r8[2], r8[3])),
                        __fadd_rn(__fadd_rn(r8[4], r8[5]), __fadd_rn(r8[6], r8[7])));
    const int kb = t * 4;
    float acc4[4] = {0.f, 0.f, 0.f, 0.f};
    const float4* cp0 = reinterpret_cast<const float4*>(cb + (size_t)(kb + 0) * D);
    const float4* cp1 = reinterpret_cast<const float4*>(cb + (size_t)(kb + 1) * D);
    const float4* cp2 = reinterpret_cast<const float4*>(cb + (size_t)(kb + 2) * D);
    const float4* cp3 = reinterpret_cast<const float4*>(cb + (size_t)(kb + 3) * D);
#pragma unroll 8
    for (int d4 = 0; d4 < 32; ++d4) {
      float4 zv = zp4[d4];
      float4 c0 = cp0[d4], c1 = cp1[d4], c2 = cp2[d4], c3 = cp3[d4];
      acc4[0] = fmaf(zv.x, c0.x, acc4[0]); acc4[0] = fmaf(zv.y, c0.y, acc4[0]);
      acc4[0] = fmaf(zv.z, c0.z, acc4[0]); acc4[0] = fmaf(zv.w, c0.w, acc4[0]);
      acc4[1] = fmaf(zv.x, c1.x, acc4[1]); acc4[1] = fmaf(zv.y, c1.y, acc4[1]);
      acc4[1] = fmaf(zv.z, c1.z, acc4[1]); acc4[1] = fmaf(zv.w, c1.w, acc4[1]);
      acc4[2] = fmaf(zv.x, c2.x, acc4[2]); acc4[2] = fmaf(zv.y, c2.y, acc4[2]);
      acc4[2] = fmaf(zv.z, c2.z, acc4[2]); acc4[2] = fmaf(zv.w, c2.w, acc4[2]);
      acc4[3] = fmaf(zv.x, c3.x, acc4[3]); acc4[3] = fmaf(zv.y, c3.y, acc4[3]);
      acc4[3] = fmaf(zv.z, c3.z, acc4[3]); acc4[3] = fmaf(zv.w, c3.w, acc4[3]);
    }
    float bd = 3.402823466e+38f; int bi = 0;
#pragma unroll
    for (int c = 0; c < 4; ++c) {
      float dist = __fadd_rn(__fsub_rn(A, __fmul_rn(2.0f, acc4[c])), CnS[kb + c]);
      if (dist < bd) { bd = dist; bi = kb + c; }
    }
    sRed[t] = bd; iRed[t] = bi;
    __syncthreads();
    for (int w = 128; w > 0; w >>= 1) {
      if (t < w) {
        float o = sRed[t + w]; int oi = iRed[t + w];
        if (o < sRed[t] || (o == sRed[t] && oi < iRed[t])) { sRed[t] = o; iRed[t] = oi; }
      }
      __syncthreads();
    }
    if (t == 0) idxArr[row] = iRed[0];
    __syncthreads();
  }

  // epilogue: gather z_q, STE, losses, index (2 threads per row)
  {
    int r = t >> 1, q = t & 1;
    int idx = idxArr[r];
    size_t m = (size_t)baseRow + r;
    const float4* cq  = reinterpret_cast<const float4*>(cb + (size_t)idx * D) + q * 16;
    const float4* zr4 = reinterpret_cast<const float4*>(z + m * D) + q * 16;
    float4*       o4  = reinterpret_cast<float4*>(out_zq + m * D) + q * 16;
    float sum = 0.f;
#pragma unroll
    for (int e = 0; e < 16; ++e) {
      float4 cv = cq[e];
      float4 zv = zr4[e];
      float dx = cv.x - zv.x, dy = cv.y - zv.y, dz = cv.z - zv.z, dw = cv.w - zv.w;
      float4 st;
      st.x = zv.x + dx; st.y = zv.y + dy; st.z = zv.z + dz; st.w = zv.w + dw;
      o4[e] = st;
      sum = fmaf(dx, dx, sum); sum = fmaf(dy, dy, sum);
      sum = fmaf(dz, dz, sum); sum = fmaf(dw, dw, sum);
    }
    sum += __shfl_xor(sum, 1, 64);
    if (q == 0) {
      float lv = sum * 0.0078125f;   // /128
      out_q[m] = lv;
      out_c[m] = lv;
      out_i[m] = (float)idx;
    }
  }
}

// ---------------- FALLBACK main: R4 kernel verbatim (validated, ~320 us) ---------------
__global__ __launch_bounds__(256) void vq_main_fp32(
    const float* __restrict__ z, const float* __restrict__ cb,
    const float* __restrict__ Cn,
    float* __restrict__ out_zq, float* __restrict__ out_q,
    float* __restrict__ out_c, float* __restrict__ out_i) {
  __shared__ float Zt[64 * D];
  __shared__ float Ct[64 * D];
  __shared__ float Arow[64];
  __shared__ int   idxArr[64];

  const int t  = threadIdx.x;
  const int ty = t >> 4;
  const int tx = t & 15;
  const int baseRow = blockIdx.x * 64;

  for (int s = t; s < 64 * (D / 4); s += 256) {
    int r = s >> 5, d4 = s & 31;
    float4 v = reinterpret_cast<const float4*>(z)[(size_t)(baseRow + r) * (D / 4) + d4];
    int colx = d4 ^ (r & 7);
    *reinterpret_cast<float4*>(&Zt[r * D + colx * 4]) = v;
  }
  __syncthreads();

  if (t < 64) {
    const int rs = t & 7;
    float r8[8];
#pragma unroll
    for (int j = 0; j < 8; ++j) {
      float v = Zt[t * D + (((j >> 2) ^ rs) << 2) + (j & 3)];
      r8[j] = __fmul_rn(v, v);
    }
    for (int i = 8; i < D; i += 8) {
#pragma unroll
      for (int j = 0; j < 8; ++j) {
        int d = i + j;
        float v = Zt[t * D + (((d >> 2) ^ rs) << 2) + (d & 3)];
        r8[j] = __fadd_rn(r8[j], __fmul_rn(v, v));
      }
    }
    Arow[t] = __fadd_rn(__fadd_rn(__fadd_rn(r8[0], r8[1]), __fadd_rn(r8[2], r8[3])),
                        __fadd_rn(__fadd_rn(r8[4], r8[5]), __fadd_rn(r8[6], r8[7])));
  }

  float s1[4]; int i1[4];
#pragma unroll
  for (int i = 0; i < 4; ++i) { s1[i] = 3.402823466e+38f; i1[i] = 0; }

  const int zsw = ty & 7;
  const int csw = tx & 7;

  for (int kt = 0; kt < 16; ++kt) {
    __syncthreads();
    for (int s = t; s < 64 * (D / 4); s += 256) {
      int r = s >> 5, d4 = s & 31;
      float4 v = reinterpret_cast<const float4*>(cb)[(size_t)(kt * 64 + r) * (D / 4) + d4];
      int colx = d4 ^ (r & 7);
      *reinterpret_cast<float4*>(&Ct[r * D + colx * 4]) = v;
    }
    __syncthreads();

    float acc[4][4];
#pragma unroll
    for (int i = 0; i < 4; ++i)
#pragma unroll
      for (int j = 0; j < 4; ++j) acc[i][j] = 0.f;

    for (int d4 = 0; d4 < 32; ++d4) {
      float4 za[4], cv[4];
      int zc = (d4 ^ zsw) * 4;
      int cc = (d4 ^ csw) * 4;
#pragma unroll
      for (int i = 0; i < 4; ++i)
        za[i] = *reinterpret_cast<const float4*>(&Zt[(ty + 16 * i) * D + zc]);
#pragma unroll
      for (int j = 0; j < 4; ++j)
        cv[j] = *reinterpret_cast<const float4*>(&Ct[(tx + 16 * j) * D + cc]);
#pragma unroll
      for (int i = 0; i < 4; ++i)
#pragma unroll
        for (int j = 0; j < 4; ++j) {
          acc[i][j] = fmaf(za[i].x, cv[j].x, acc[i][j]);
          acc[i][j] = fmaf(za[i].y, cv[j].y, acc[i][j]);
          acc[i][j] = fmaf(za[i].z, cv[j].z, acc[i][j]);
          acc[i][j] = fmaf(za[i].w, cv[j].w, acc[i][j]);
        }
    }

    float ch[4]; int kg[4];
#pragma unroll
    for (int j = 0; j < 4; ++j) {
      kg[j] = kt * 64 + tx + 16 * j;
      ch[j] = Cn[kg[j]];
    }
#pragma unroll
    for (int i = 0; i < 4; ++i) {
      float a = Arow[ty + 16 * i];
#pragma unroll
      for (int j = 0; j < 4; ++j) {
        float dist = __fadd_rn(__fsub_rn(a, __fmul_rn(2.0f, acc[i][j])), ch[j]);
        if (dist < s1[i]) { s1[i] = dist; i1[i] = kg[j]; }
      }
    }
  }

#pragma unroll
  for (int m = 1; m < 16; m <<= 1) {
#pragma unroll
    for (int i = 0; i < 4; ++i) {
      float os = __shfl_xor(s1[i], m, 64);
      int   oi = __shfl_xor(i1[i], m, 64);
      if (os < s1[i] || (os == s1[i] && oi < i1[i])) { s1[i] = os; i1[i] = oi; }
    }
  }

  if (tx == 0) {
#pragma unroll
    for (int i = 0; i < 4; ++i) idxArr[ty + 16 * i] = i1[i];
  }
  __syncthreads();

  {
    int r = t >> 2, q = t & 3;
    int idx = idxArr[r];
    size_t m = (size_t)baseRow + r;
    const float4* cq = reinterpret_cast<const float4*>(cb + (size_t)idx * D);
    const float4* zr = reinterpret_cast<const float4*>(z + m * D);
    float4*       o4 = reinterpret_cast<float4*>(out_zq + m * D);
    float sum = 0.f;
#pragma unroll
    for (int e = 0; e < 8; ++e) {
      int d4 = q * 8 + e;
      float4 cv = cq[d4];
      float4 zv = zr[d4];
      float dx = cv.x - zv.x, dy = cv.y - zv.y, dz = cv.z - zv.z, dw = cv.w - zv.w;
      float4 st;
      st.x = zv.x + dx; st.y = zv.y + dy; st.z = zv.z + dz; st.w = zv.w + dw;
      o4[d4] = st;
      sum = fmaf(dx, dx, sum); sum = fmaf(dy, dy, sum);
      sum = fmaf(dz, dz, sum); sum = fmaf(dw, dw, sum);
    }
    sum += __shfl_xor(sum, 1, 64);
    sum += __shfl_xor(sum, 2, 64);
    if (q == 0) {
      float lv = sum * 0.0078125f;
      out_q[m] = lv;
      out_c[m] = lv;
      out_i[m] = (float)idx;
    }
  }
}

extern "C" void kernel_launch(void* const* d_in, const int* in_sizes, int n_in,
                              void* d_out, int out_size, void* d_ws, size_t ws_size,
                              hipStream_t stream) {
  const float* z  = (const float*)d_in[0];   // [16,4096,128] fp32
  const float* cb = (const float*)d_in[1];   // [1024,128] fp32

  float* out0 = (float*)d_out;               // z_q_ste  [M,128]
  float* out1 = out0 + (size_t)M_TOTAL * D;  // quant_loss [M]
  float* out2 = out1 + M_TOTAL;              // commit_loss [M]
  float* out3 = out2 + M_TOTAL;              // indices (as float) [M]

  float* Cn = (float*)((char*)d_ws + WS_CN);
  vq_prep<<<(K + 255) / 256, 256, 0, stream>>>(cb, Cn);

  if (ws_size >= WS_REQ) {
    short* Bh = (short*)((char*)d_ws + WS_BH);
    short* Bl = (short*)((char*)d_ws + WS_BL);
    vq_frag<<<64, 256, 0, stream>>>(cb, Bh, Bl);
    vq_main_frag<<<M_TOTAL / BM, 256, 0, stream>>>(z, cb, Cn, Bh, Bl,
                                                   out0, out1, out2, out3);
  } else {
    vq_main_fp32<<<M_TOTAL / 64, 256, 0, stream>>>(z, cb, Cn, out0, out1, out2, out3);
  }
}